// Round 8
// baseline (365.863 us; speedup 1.0000x reference)
//
#include <hip/hip_runtime.h>

typedef __attribute__((ext_vector_type(8))) short bf16x8;
typedef __attribute__((ext_vector_type(8))) unsigned short u16x8;
typedef __attribute__((ext_vector_type(4))) unsigned short u16x4;
typedef __attribute__((ext_vector_type(4))) float f32x4;
typedef unsigned short u16t;

#define MFMA16(a, b, c) __builtin_amdgcn_mfma_f32_16x16x32_bf16((a), (b), (c), 0, 0, 0)
#define GLDS16(gp, lp)                                                        \
  __builtin_amdgcn_global_load_lds(                                           \
      (__attribute__((address_space(1))) void*)(gp),                          \
      (__attribute__((address_space(3))) void*)(lp), 16, 0, 0)

static constexpr float L2E = 1.44269504f;   // log2(e)
static constexpr float MASKV = -1.0e30f;    // finite mask sentinel (no inf paths)

__device__ __forceinline__ u16t f2b(float f) {
  unsigned u = __builtin_bit_cast(unsigned, f);
  u = u + 0x7fffu + ((u >> 16) & 1u); // RNE
  return (u16t)(u >> 16);
}

// ---------------------------------------------------------------------------
// fp32 -> bf16 conversion of x and the 4 weight matrices, one fused launch.
// ---------------------------------------------------------------------------
__global__ void cvt5(const float* __restrict__ x, const float* __restrict__ wq,
                     const float* __restrict__ wk, const float* __restrict__ wv,
                     const float* __restrict__ wo, u16t* __restrict__ xb,
                     u16t* __restrict__ wqb, u16t* __restrict__ wkb,
                     u16t* __restrict__ wvb, u16t* __restrict__ wob) {
  const int bid = blockIdx.x;
  const float* src; u16t* dst; int gb;
  if (bid < 4096)      { src = x;  dst = xb;  gb = bid; }
  else if (bid < 4608) { src = wq; dst = wqb; gb = bid - 4096; }
  else if (bid < 5120) { src = wk; dst = wkb; gb = bid - 4608; }
  else if (bid < 5632) { src = wv; dst = wvb; gb = bid - 5120; }
  else                 { src = wo; dst = wob; gb = bid - 5632; }
  const size_t i = (size_t)gb * 256 + threadIdx.x; // 8-elem group index
  const float4 a = ((const float4*)src)[2 * i];
  const float4 b = ((const float4*)src)[2 * i + 1];
  u16x8 r;
  r[0] = f2b(a.x); r[1] = f2b(a.y); r[2] = f2b(a.z); r[3] = f2b(a.w);
  r[4] = f2b(b.x); r[5] = f2b(b.y); r[6] = f2b(b.z); r[7] = f2b(b.w);
  *(u16x8*)&dst[8 * i] = r;
}

// ---------------------------------------------------------------------------
// GEMM core (m97 structure). z=2 (V) writes TRANSPOSED output V^T[b][h][hd][s]
// so the attention PV step reads B-fragments directly from global with
// vectorized loads. (Unchanged -- passed rounds 4/5/6.)
// ---------------------------------------------------------------------------
__global__ void gemm_qkv(const u16t* __restrict__ X,
                         const u16t* __restrict__ Wq, const u16t* __restrict__ Wk,
                         const u16t* __restrict__ Wv,
                         const float* __restrict__ bq, const float* __restrict__ bk,
                         const float* __restrict__ bv,
                         u16t* __restrict__ Qo, u16t* __restrict__ Ko,
                         u16t* __restrict__ Vo) {
  __shared__ __align__(16) u16t As[128 * 32];
  __shared__ __align__(16) u16t Bs[128 * 32];
  const int t = threadIdx.x, lane = t & 63, w = t >> 6;
  const int wr = w >> 1, wc = w & 1, m = lane & 15, quad = lane >> 4;
  const int rowBase = blockIdx.y * 128, colBase = blockIdx.x * 128;
  const int z = blockIdx.z;
  const u16t* W = (z == 0) ? Wq : ((z == 1) ? Wk : Wv);
  const float* bias = (z == 0) ? bq : ((z == 1) ? bk : bv);
  u16t* Out = (z == 0) ? Qo : ((z == 1) ? Ko : Vo);

  f32x4 acc[4][4];
#pragma unroll
  for (int i = 0; i < 4; i++)
#pragma unroll
    for (int j = 0; j < 4; j++) acc[i][j] = (f32x4){0.f, 0.f, 0.f, 0.f};

  const int lr = lane >> 2, lc = (lane & 3) * 8;
  for (int kt = 0; kt < 32; ++kt) {
#pragma unroll
    for (int i = 0; i < 2; ++i) {
      const int r0 = i * 64 + w * 16;
      GLDS16(&X[(size_t)(rowBase + r0 + lr) * 1024 + kt * 32 + lc], &As[r0 * 32]);
      GLDS16(&W[(size_t)(colBase + r0 + lr) * 1024 + kt * 32 + lc], &Bs[r0 * 32]);
    }
    __syncthreads();
    bf16x8 af[4], bfr[4];
#pragma unroll
    for (int i = 0; i < 4; i++)
      af[i] = *(const bf16x8*)&As[(wr * 64 + i * 16 + m) * 32 + quad * 8];
#pragma unroll
    for (int j = 0; j < 4; j++)
      bfr[j] = *(const bf16x8*)&Bs[(wc * 64 + j * 16 + m) * 32 + quad * 8];
#pragma unroll
    for (int i = 0; i < 4; i++)
#pragma unroll
      for (int j = 0; j < 4; j++) acc[i][j] = MFMA16(af[i], bfr[j], acc[i][j]);
    __syncthreads();
  }

  const int b_ = rowBase >> 10;          // whole block is in one batch row
  const int sBase = (rowBase & 1023) + wr * 64;
#pragma unroll
  for (int j = 0; j < 4; j++) {
    const int col = colBase + wc * 64 + j * 16 + m;
    const float bv_ = bias[col];
    const int h = col >> 6, hd = col & 63;
    if (z == 2) {
      // V^T: Out[((b*16+h)*64 + hd)*1024 + s], 4 consecutive s per u16x4
#pragma unroll
      for (int i = 0; i < 4; i++) {
        const int s0 = sBase + i * 16 + quad * 4;
        u16x4 pk;
#pragma unroll
        for (int r = 0; r < 4; r++) pk[r] = f2b(acc[i][j][r] + bv_);
        *(u16x4*)&Out[(((size_t)b_ * 16 + h) * 64 + hd) * 1024 + s0] = pk;
      }
    } else {
#pragma unroll
      for (int i = 0; i < 4; i++) {
#pragma unroll
        for (int r = 0; r < 4; r++) {
          const int s_ = sBase + i * 16 + quad * 4 + r;
          const size_t oi = (((size_t)b_ * 16 + h) * 1024 + s_) * 64 + hd;
          Out[oi] = f2b(acc[i][j][r] + bv_);
        }
      }
    }
  }
}

__global__ void gemm_o(const u16t* __restrict__ A, const u16t* __restrict__ W,
                       const float* __restrict__ bias, float* __restrict__ Out) {
  __shared__ __align__(16) u16t As[128 * 32];
  __shared__ __align__(16) u16t Bs[128 * 32];
  const int t = threadIdx.x, lane = t & 63, w = t >> 6;
  const int wr = w >> 1, wc = w & 1, m = lane & 15, quad = lane >> 4;
  const int rowBase = blockIdx.y * 128, colBase = blockIdx.x * 128;

  f32x4 acc[4][4];
#pragma unroll
  for (int i = 0; i < 4; i++)
#pragma unroll
    for (int j = 0; j < 4; j++) acc[i][j] = (f32x4){0.f, 0.f, 0.f, 0.f};

  const int lr = lane >> 2, lc = (lane & 3) * 8;
  for (int kt = 0; kt < 32; ++kt) {
#pragma unroll
    for (int i = 0; i < 2; ++i) {
      const int r0 = i * 64 + w * 16;
      GLDS16(&A[(size_t)(rowBase + r0 + lr) * 1024 + kt * 32 + lc], &As[r0 * 32]);
      GLDS16(&W[(size_t)(colBase + r0 + lr) * 1024 + kt * 32 + lc], &Bs[r0 * 32]);
    }
    __syncthreads();
    bf16x8 af[4], bfr[4];
#pragma unroll
    for (int i = 0; i < 4; i++)
      af[i] = *(const bf16x8*)&As[(wr * 64 + i * 16 + m) * 32 + quad * 8];
#pragma unroll
    for (int j = 0; j < 4; j++)
      bfr[j] = *(const bf16x8*)&Bs[(wc * 64 + j * 16 + m) * 32 + quad * 8];
#pragma unroll
    for (int i = 0; i < 4; i++)
#pragma unroll
      for (int j = 0; j < 4; j++) acc[i][j] = MFMA16(af[i], bfr[j], acc[i][j]);
    __syncthreads();
  }

#pragma unroll
  for (int j = 0; j < 4; j++) {
    const int col = colBase + wc * 64 + j * 16 + m;
    const float bv_ = bias[col];
#pragma unroll
    for (int i = 0; i < 4; i++) {
#pragma unroll
      for (int r = 0; r < 4; r++) {
        const int row = rowBase + wr * 64 + i * 16 + quad * 4 + r;
        Out[(size_t)row * 1024 + col] = acc[i][j][r] + bv_;
      }
    }
  }
}

// ---------------------------------------------------------------------------
// Flash attention v8: SWAPPED QK^T -> per-lane scalar online softmax.
//  - S^T = MFMA16(kf, qf): C col = lane&15 = q-local, row = quad*4+r = key.
//    Each lane's 16 scores (4nt x 4r) belong to ONE q row (q = qbase+m);
//    lanes {m, m+16, m+32, m+48} hold disjoint key subsets of that row.
//  - Row reduce: in-lane fmax/add tree + 2 hops (xor16, xor32) [was 16 ops].
//    mi/li/alpha are per-lane SCALARS [was x4 arrays].
//  - Pad+causal fused into one u64: km2 = maskL[kt] & causal64(q,kt); per
//    element = const-shift bit test.
//  - Defer-max (THR=8): rescale branch skipped when !__any(pmax > mi+8)
//    (~99% of tiles). P bounded by e^8 -- bf16-safe; mi cancels in o/li.
//  - P -> bf16 via v_cvt_pk_bf16_f32 (8 instr, RNE) + 4 ds_write_b64.
//    P reads + all K/Q/V fragment addresses bit-identical to v7 (verified).
//  - Keeps: uniform (p,15-p) wave pairing, XCD-affine decode, immediate-use
//    loads only (no cross-tile register arrays -> no spills).
// ---------------------------------------------------------------------------
__global__ __launch_bounds__(256) void attn(
    const u16t* __restrict__ Q, const u16t* __restrict__ K,
    const u16t* __restrict__ VT, const int* __restrict__ ids,
    u16t* __restrict__ Oo) {
  constexpr int PSTR = 72;
  __shared__ __align__(16) u16t Ps[4][16 * PSTR];
  __shared__ unsigned long long maskL[16];

  const int t = threadIdx.x, lane = t & 63, wl = t >> 6;  // wl: 0..3
  const int m = lane & 15, quad = lane >> 4;
  const int id = blockIdx.x;
  const int g = id & 7, k_ = id >> 3;
  const int bh = g + 8 * (k_ & 15);
  const int p = k_ >> 4;                 // pair index 0..7
  const int b = bh >> 4, h = bh & 15;
  const size_t hoff = (size_t)bh * 65536;   // 1024 * 64

  // ---- pad-key bitmask (one u64 per 64-key tile) ----
#pragma unroll
  for (int c = 0; c < 4; ++c) {
    const int chunk = wl * 4 + c;
    const int idv = ids[b * 1024 + chunk * 64 + lane];
    const unsigned long long mk = __ballot(idv != 1);
    if (lane == 0) maskL[chunk] = mk;
  }
  __syncthreads();   // the only block-wide barrier

  u16t* const Pw = &Ps[wl][0];

  for (int pass = 0; pass < 2; ++pass) {
    const int qt = pass ? (15 - p) : p;
    const int qbase = qt * 64 + wl * 16;
    const int qrow = qbase + m;          // this lane's softmax row

    const bf16x8 qf0 =
        *(const bf16x8*)&Q[hoff + (size_t)(qbase + m) * 64 + quad * 8];
    const bf16x8 qf1 =
        *(const bf16x8*)&Q[hoff + (size_t)(qbase + m) * 64 + 32 + quad * 8];

    float mi = MASKV, li = 0.f;
    f32x4 o[4];
#pragma unroll
    for (int ot = 0; ot < 4; ot++) o[ot] = (f32x4){0.f, 0.f, 0.f, 0.f};

    for (int kt = 0; kt <= qt; ++kt) {
      // ---- fused pad+causal mask for this lane's row ----
      const int dq0 = qrow - kt * 64;              // >= 0 while kt <= qt
      const int dqc = dq0 > 63 ? 63 : dq0;
      const unsigned long long causal =
          (dqc == 63) ? ~0ull : ((1ull << (dqc + 1)) - 1ull);
      const unsigned long long km2 = maskL[kt] & causal;
      const unsigned kqlo = (unsigned)(km2 >> (quad * 4));
      const unsigned kqhi = (unsigned)(km2 >> (quad * 4 + 32));

      // ---- scores S^T: lane holds S[key=nt*16+quad*4+r][q=qrow] ----
      f32x4 sc[4];
      float pm = MASKV;
#pragma unroll
      for (int nt = 0; nt < 4; nt++) {
        if ((kt * 64 + nt * 16) <= (qbase + 15)) { // wave-uniform skip
          const size_t krow = hoff + (size_t)(kt * 64 + nt * 16 + m) * 64;
          const bf16x8 k0 = *(const bf16x8*)&K[krow + quad * 8];
          const bf16x8 k1 = *(const bf16x8*)&K[krow + 32 + quad * 8];
          f32x4 c = (f32x4){0.f, 0.f, 0.f, 0.f};
          c = MFMA16(k0, qf0, c);     // SWAPPED: A=K (row=key), B=Q (col=q)
          c = MFMA16(k1, qf1, c);
          const unsigned w32 = (nt < 2) ? kqlo : kqhi;
#pragma unroll
          for (int r = 0; r < 4; r++) {
            const int sh = (nt & 1) * 16 + r;      // compile-time
            const float s = ((w32 >> sh) & 1u) ? c[r] * 0.125f : MASKV;
            sc[nt][r] = s;
            pm = fmaxf(pm, s);
          }
        } else {
#pragma unroll
          for (int r = 0; r < 4; r++) sc[nt][r] = MASKV;
        }
      }
      // cross-lane max over the 4 key-subsets of this row
      pm = fmaxf(pm, __shfl_xor(pm, 16));
      pm = fmaxf(pm, __shfl_xor(pm, 32));

      // ---- defer-max: rescale only when some row grew past THR=8 ----
      if (__any(pm > mi + 8.0f)) {
        const float mn = (pm > mi + 8.0f) ? pm : mi;
        const float alpha = exp2f((mi - mn) * L2E);
        mi = mn;
        li *= alpha;
#pragma unroll
        for (int r = 0; r < 4; r++) {
          const float ar = __shfl(alpha, quad * 4 + r);
#pragma unroll
          for (int ot = 0; ot < 4; ot++) o[ot][r] *= ar;
        }
      }

      // ---- P = exp2(sc - mi); pack via cvt_pk; 4x ds_write_b64 ----
      float rsum = 0.f;
#pragma unroll
      for (int nt = 0; nt < 4; nt++) {
        float pf[4];
#pragma unroll
        for (int r = 0; r < 4; r++) {
          pf[r] = exp2f((sc[nt][r] - mi) * L2E);  // masked -> exp2(-1e30)=0
          rsum += pf[r];
        }
        unsigned w0, w1;
        asm("v_cvt_pk_bf16_f32 %0, %1, %2" : "=v"(w0) : "v"(pf[0]), "v"(pf[1]));
        asm("v_cvt_pk_bf16_f32 %0, %1, %2" : "=v"(w1) : "v"(pf[2]), "v"(pf[3]));
        uint2 wv; wv.x = w0; wv.y = w1;
        *(uint2*)&Pw[m * PSTR + nt * 16 + quad * 4] = wv;
      }
      rsum += __shfl_xor(rsum, 16);
      rsum += __shfl_xor(rsum, 32);
      li += rsum;

      // ---- P @ V (P rows=q via per-wave LDS; V^T immediate-use) ----
      const bf16x8 p0 = *(const bf16x8*)&Pw[m * PSTR + quad * 8];
      const bf16x8 p1 = *(const bf16x8*)&Pw[m * PSTR + 32 + quad * 8];
#pragma unroll
      for (int ot = 0; ot < 4; ot++) {
        const size_t vrow = hoff + (size_t)(ot * 16 + m) * 1024 + kt * 64;
        const bf16x8 v0 = *(const bf16x8*)&VT[vrow + quad * 8];
        const bf16x8 v1 = *(const bf16x8*)&VT[vrow + 32 + quad * 8];
        o[ot] = MFMA16(p0, v0, o[ot]);
        o[ot] = MFMA16(p1, v1, o[ot]);
      }
    }

    // ---- epilogue: o rows = q = qbase+quad*4+r; li lives at lane q&15 ----
    const float linv = (li > 1e-30f) ? 1.f / li : 0.f;
#pragma unroll
    for (int r = 0; r < 4; r++) {
      const float inv = __shfl(linv, quad * 4 + r);
      const int qo = qbase + quad * 4 + r;
#pragma unroll
      for (int ot = 0; ot < 4; ot++) {
        const int col = h * 64 + ot * 16 + m;
        Oo[((size_t)(b * 1024 + qo)) * 1024 + col] = f2b(o[ot][r] * inv);
      }
    }
  }
}

// ---------------------------------------------------------------------------
extern "C" void kernel_launch(void* const* d_in, const int* in_sizes, int n_in,
                              void* d_out, int out_size, void* d_ws, size_t ws_size,
                              hipStream_t stream) {
  const float* x  = (const float*)d_in[0];
  const int*   ids = (const int*)d_in[1];
  const float* Wq = (const float*)d_in[2];
  const float* bq = (const float*)d_in[3];
  const float* Wk = (const float*)d_in[4];
  const float* bk = (const float*)d_in[5];
  const float* Wv = (const float*)d_in[6];
  const float* bv = (const float*)d_in[7];
  const float* Wo = (const float*)d_in[8];
  const float* bo = (const float*)d_in[9];
  float* out = (float*)d_out;

  // ws layout (bf16 elems): XB 8.4M | WqB,WkB,WvB,WoB 1M each | Q,K,V 8.4M each
  u16t* XB  = (u16t*)d_ws;
  u16t* WqB = XB  + 8388608;
  u16t* WkB = WqB + 1048576;
  u16t* WvB = WkB + 1048576;
  u16t* WoB = WvB + 1048576;
  u16t* Qw  = WoB + 1048576;
  u16t* Kw  = Qw  + 8388608;
  u16t* Vw  = Kw  + 8388608;   // holds V^T[b][h][hd][s]
  u16t* AO  = XB; // reuse after gemm_qkv consumed XB

  cvt5<<<6144, 256, 0, stream>>>(x, Wq, Wk, Wv, Wo, XB, WqB, WkB, WvB, WoB);
  gemm_qkv<<<dim3(8, 64, 3), 256, 0, stream>>>(XB, WqB, WkB, WvB, bq, bk, bv,
                                               Qw, Kw, Vw);
  attn<<<1024, 256, 0, stream>>>(Qw, Kw, Vw, ids, AO);
  gemm_o<<<dim3(8, 64, 1), 256, 0, stream>>>(AO, WoB, bo, out);
}

// Round 9
// 265.260 us; speedup vs baseline: 1.3793x; 1.3793x over previous
//
#include <hip/hip_runtime.h>

typedef __attribute__((ext_vector_type(8))) short bf16x8;
typedef __attribute__((ext_vector_type(8))) unsigned short u16x8;
typedef __attribute__((ext_vector_type(4))) unsigned short u16x4;
typedef __attribute__((ext_vector_type(4))) float f32x4;
typedef unsigned short u16t;

#define MFMA16(a, b, c) __builtin_amdgcn_mfma_f32_16x16x32_bf16((a), (b), (c), 0, 0, 0)
#define GLDS16(gp, lp)                                                        \
  __builtin_amdgcn_global_load_lds(                                           \
      (__attribute__((address_space(1))) void*)(gp),                          \
      (__attribute__((address_space(3))) void*)(lp), 16, 0, 0)

static constexpr float L2E = 1.44269504f;   // log2(e)
static constexpr float MASKV = -1.0e30f;    // finite mask sentinel (no inf paths)

__device__ __forceinline__ u16t f2b(float f) {
  unsigned u = __builtin_bit_cast(unsigned, f);
  u = u + 0x7fffu + ((u >> 16) & 1u); // RNE
  return (u16t)(u >> 16);
}

// ---------------------------------------------------------------------------
// fp32 -> bf16 conversion of x and the 4 weight matrices, one fused launch.
// ---------------------------------------------------------------------------
__global__ void cvt5(const float* __restrict__ x, const float* __restrict__ wq,
                     const float* __restrict__ wk, const float* __restrict__ wv,
                     const float* __restrict__ wo, u16t* __restrict__ xb,
                     u16t* __restrict__ wqb, u16t* __restrict__ wkb,
                     u16t* __restrict__ wvb, u16t* __restrict__ wob) {
  const int bid = blockIdx.x;
  const float* src; u16t* dst; int gb;
  if (bid < 4096)      { src = x;  dst = xb;  gb = bid; }
  else if (bid < 4608) { src = wq; dst = wqb; gb = bid - 4096; }
  else if (bid < 5120) { src = wk; dst = wkb; gb = bid - 4608; }
  else if (bid < 5632) { src = wv; dst = wvb; gb = bid - 5120; }
  else                 { src = wo; dst = wob; gb = bid - 5632; }
  const size_t i = (size_t)gb * 256 + threadIdx.x; // 8-elem group index
  const float4 a = ((const float4*)src)[2 * i];
  const float4 b = ((const float4*)src)[2 * i + 1];
  u16x8 r;
  r[0] = f2b(a.x); r[1] = f2b(a.y); r[2] = f2b(a.z); r[3] = f2b(a.w);
  r[4] = f2b(b.x); r[5] = f2b(b.y); r[6] = f2b(b.z); r[7] = f2b(b.w);
  *(u16x8*)&dst[8 * i] = r;
}

// ---------------------------------------------------------------------------
// GEMM core (m97 structure). z=2 (V) writes TRANSPOSED output V^T[b][h][hd][s]
// so the attention PV step reads B-fragments from V^T. (Unchanged -- passed.)
// ---------------------------------------------------------------------------
__global__ void gemm_qkv(const u16t* __restrict__ X,
                         const u16t* __restrict__ Wq, const u16t* __restrict__ Wk,
                         const u16t* __restrict__ Wv,
                         const float* __restrict__ bq, const float* __restrict__ bk,
                         const float* __restrict__ bv,
                         u16t* __restrict__ Qo, u16t* __restrict__ Ko,
                         u16t* __restrict__ Vo) {
  __shared__ __align__(16) u16t As[128 * 32];
  __shared__ __align__(16) u16t Bs[128 * 32];
  const int t = threadIdx.x, lane = t & 63, w = t >> 6;
  const int wr = w >> 1, wc = w & 1, m = lane & 15, quad = lane >> 4;
  const int rowBase = blockIdx.y * 128, colBase = blockIdx.x * 128;
  const int z = blockIdx.z;
  const u16t* W = (z == 0) ? Wq : ((z == 1) ? Wk : Wv);
  const float* bias = (z == 0) ? bq : ((z == 1) ? bk : bv);
  u16t* Out = (z == 0) ? Qo : ((z == 1) ? Ko : Vo);

  f32x4 acc[4][4];
#pragma unroll
  for (int i = 0; i < 4; i++)
#pragma unroll
    for (int j = 0; j < 4; j++) acc[i][j] = (f32x4){0.f, 0.f, 0.f, 0.f};

  const int lr = lane >> 2, lc = (lane & 3) * 8;
  for (int kt = 0; kt < 32; ++kt) {
#pragma unroll
    for (int i = 0; i < 2; ++i) {
      const int r0 = i * 64 + w * 16;
      GLDS16(&X[(size_t)(rowBase + r0 + lr) * 1024 + kt * 32 + lc], &As[r0 * 32]);
      GLDS16(&W[(size_t)(colBase + r0 + lr) * 1024 + kt * 32 + lc], &Bs[r0 * 32]);
    }
    __syncthreads();
    bf16x8 af[4], bfr[4];
#pragma unroll
    for (int i = 0; i < 4; i++)
      af[i] = *(const bf16x8*)&As[(wr * 64 + i * 16 + m) * 32 + quad * 8];
#pragma unroll
    for (int j = 0; j < 4; j++)
      bfr[j] = *(const bf16x8*)&Bs[(wc * 64 + j * 16 + m) * 32 + quad * 8];
#pragma unroll
    for (int i = 0; i < 4; i++)
#pragma unroll
      for (int j = 0; j < 4; j++) acc[i][j] = MFMA16(af[i], bfr[j], acc[i][j]);
    __syncthreads();
  }

  const int b_ = rowBase >> 10;          // whole block is in one batch row
  const int sBase = (rowBase & 1023) + wr * 64;
#pragma unroll
  for (int j = 0; j < 4; j++) {
    const int col = colBase + wc * 64 + j * 16 + m;
    const float bv_ = bias[col];
    const int h = col >> 6, hd = col & 63;
    if (z == 2) {
      // V^T: Out[((b*16+h)*64 + hd)*1024 + s], 4 consecutive s per u16x4
#pragma unroll
      for (int i = 0; i < 4; i++) {
        const int s0 = sBase + i * 16 + quad * 4;
        u16x4 pk;
#pragma unroll
        for (int r = 0; r < 4; r++) pk[r] = f2b(acc[i][j][r] + bv_);
        *(u16x4*)&Out[(((size_t)b_ * 16 + h) * 64 + hd) * 1024 + s0] = pk;
      }
    } else {
#pragma unroll
      for (int i = 0; i < 4; i++) {
#pragma unroll
        for (int r = 0; r < 4; r++) {
          const int s_ = sBase + i * 16 + quad * 4 + r;
          const size_t oi = (((size_t)b_ * 16 + h) * 1024 + s_) * 64 + hd;
          Out[oi] = f2b(acc[i][j][r] + bv_);
        }
      }
    }
  }
}

__global__ void gemm_o(const u16t* __restrict__ A, const u16t* __restrict__ W,
                       const float* __restrict__ bias, float* __restrict__ Out) {
  __shared__ __align__(16) u16t As[128 * 32];
  __shared__ __align__(16) u16t Bs[128 * 32];
  const int t = threadIdx.x, lane = t & 63, w = t >> 6;
  const int wr = w >> 1, wc = w & 1, m = lane & 15, quad = lane >> 4;
  const int rowBase = blockIdx.y * 128, colBase = blockIdx.x * 128;

  f32x4 acc[4][4];
#pragma unroll
  for (int i = 0; i < 4; i++)
#pragma unroll
    for (int j = 0; j < 4; j++) acc[i][j] = (f32x4){0.f, 0.f, 0.f, 0.f};

  const int lr = lane >> 2, lc = (lane & 3) * 8;
  for (int kt = 0; kt < 32; ++kt) {
#pragma unroll
    for (int i = 0; i < 2; ++i) {
      const int r0 = i * 64 + w * 16;
      GLDS16(&A[(size_t)(rowBase + r0 + lr) * 1024 + kt * 32 + lc], &As[r0 * 32]);
      GLDS16(&W[(size_t)(colBase + r0 + lr) * 1024 + kt * 32 + lc], &Bs[r0 * 32]);
    }
    __syncthreads();
    bf16x8 af[4], bfr[4];
#pragma unroll
    for (int i = 0; i < 4; i++)
      af[i] = *(const bf16x8*)&As[(wr * 64 + i * 16 + m) * 32 + quad * 8];
#pragma unroll
    for (int j = 0; j < 4; j++)
      bfr[j] = *(const bf16x8*)&Bs[(wc * 64 + j * 16 + m) * 32 + quad * 8];
#pragma unroll
    for (int i = 0; i < 4; i++)
#pragma unroll
      for (int j = 0; j < 4; j++) acc[i][j] = MFMA16(af[i], bfr[j], acc[i][j]);
    __syncthreads();
  }

#pragma unroll
  for (int j = 0; j < 4; j++) {
    const int col = colBase + wc * 64 + j * 16 + m;
    const float bv_ = bias[col];
#pragma unroll
    for (int i = 0; i < 4; i++) {
#pragma unroll
      for (int r = 0; r < 4; r++) {
        const int row = rowBase + wr * 64 + i * 16 + quad * 4 + r;
        Out[(size_t)row * 1024 + col] = acc[i][j][r] + bv_;
      }
    }
  }
}

// ---------------------------------------------------------------------------
// Flash attention v9: BLOCK-COOPERATIVE LDS STAGING (8 waves share K/V).
//  - 512 blocks x 512 thr. Block = (bh, p4); passes qt8 = p4 then 7-p4 over a
//    128-row q-tile (wave wl owns rows qbase=qt8*128+wl*16..+15). Every wave:
//    exactly 18 kt-iters. XCD-affine (id&7 = bh&7); 2 blocks/CU resident.
//  - K and V^T 64-tiles staged ONCE per block via global_load_lds (2 instrs
//    per wave per tile), double-buffered, prefetch issued before compute so
//    the __syncthreads vmcnt-drain overlaps compute (m97 pattern). Global
//    traffic drops 8x vs v8's per-wave re-reads (the 167us wall: memory-pipe
//    saturation at ~1.1 GB of L2/L3 transactions with all util counters low).
//  - Swizzle: round-2-verified XOR-granule. Source granule g^=(row&7) with
//    linear LDS dest; read granule = quad^(m&7) (k0/v0), (quad+4)^(m&7)
//    (k1/v1). Uniform 8-lanes-per-4-bank distribution = minimum-phase b128.
//  - Compute: v8 verbatim (swapped QK^T, per-lane scalar online softmax,
//    defer-max THR=8, cvt_pk P-pack, P via per-wave LDS, MFMA PV).
// ---------------------------------------------------------------------------
__global__ __launch_bounds__(512) void attn(
    const u16t* __restrict__ Q, const u16t* __restrict__ K,
    const u16t* __restrict__ VT, const int* __restrict__ ids,
    u16t* __restrict__ Oo) {
  constexpr int PSTR = 72;
  __shared__ __align__(16) u16t Kb[2][64 * 64];
  __shared__ __align__(16) u16t Vb[2][64 * 64];
  __shared__ __align__(16) u16t Ps[8][16 * PSTR];
  __shared__ unsigned long long maskL[16];

  const int t = threadIdx.x, lane = t & 63, wl = t >> 6;  // wl: 0..7
  const int m = lane & 15, quad = lane >> 4;
  const int id = blockIdx.x;
  const int g = id & 7, k_ = id >> 3;
  const int bh = g + 8 * (k_ & 15);
  const int p4 = k_ >> 4;                // 0..3
  const int b = bh >> 4, h = bh & 15;
  const size_t hoff = (size_t)bh * 65536;   // 1024 * 64

  // staging geometry: wave wl stages rows wl*8..+7 of each 64-row tile;
  // lane: row = wl*8 + (lane>>3), source granule = (lane&7) ^ ((lane>>3)&7).
  const int srow = lane >> 3;
  const int sg = (lane & 7) ^ (srow & 7);

  // ---- pad-key bitmask (one u64 per 64-key tile) ----
#pragma unroll
  for (int c = 0; c < 2; ++c) {
    const int chunk = wl * 2 + c;
    const int idv = ids[b * 1024 + chunk * 64 + lane];
    const unsigned long long mk = __ballot(idv != 1);
    if (lane == 0) maskL[chunk] = mk;
  }
  __syncthreads();

  u16t* const Pw = &Ps[wl][0];

  for (int pass = 0; pass < 2; ++pass) {
    const int qt8 = pass ? (7 - p4) : p4;
    const int qbase = qt8 * 128 + wl * 16;
    const int qrow = qbase + m;          // this lane's softmax row
    const int ktmax = 2 * qt8 + 1;

    // ---- stage tile 0 (pass A ends on odd buffer, so buf0 is free) ----
    GLDS16(&K[hoff + (size_t)(wl * 8 + srow) * 64 + sg * 8], &Kb[0][wl * 512]);
    GLDS16(&VT[hoff + (size_t)(wl * 8 + srow) * 1024 + sg * 8], &Vb[0][wl * 512]);

    const bf16x8 qf0 =
        *(const bf16x8*)&Q[hoff + (size_t)(qbase + m) * 64 + quad * 8];
    const bf16x8 qf1 =
        *(const bf16x8*)&Q[hoff + (size_t)(qbase + m) * 64 + 32 + quad * 8];

    float mi = MASKV, li = 0.f;
    f32x4 o[4];
#pragma unroll
    for (int ot = 0; ot < 4; ot++) o[ot] = (f32x4){0.f, 0.f, 0.f, 0.f};

    __syncthreads();   // buf0 staged (drains vmcnt)

    for (int kt = 0; kt <= ktmax; ++kt) {
      // prefetch next tile into the other buffer (drained at end barrier)
      if (kt < ktmax) {
        u16t* const kb = &Kb[(kt + 1) & 1][wl * 512];
        u16t* const vb = &Vb[(kt + 1) & 1][wl * 512];
        GLDS16(&K[hoff + (size_t)((kt + 1) * 64 + wl * 8 + srow) * 64 + sg * 8], kb);
        GLDS16(&VT[hoff + (size_t)(wl * 8 + srow) * 1024 + (kt + 1) * 64 + sg * 8], vb);
      }

      if (kt * 64 <= qbase + 15) {       // wave-uniform: any causal work?
        const u16t* const Kc = Kb[kt & 1];
        const u16t* const Vc = Vb[kt & 1];

        // ---- fused pad+causal mask for this lane's row ----
        const int dq0 = qrow - kt * 64;            // >= 0 inside guard
        const int dqc = dq0 > 63 ? 63 : dq0;
        const unsigned long long causal =
            (dqc == 63) ? ~0ull : ((1ull << (dqc + 1)) - 1ull);
        const unsigned long long km2 = maskL[kt] & causal;
        const unsigned kqlo = (unsigned)(km2 >> (quad * 4));
        const unsigned kqhi = (unsigned)(km2 >> (quad * 4 + 32));

        // ---- scores S^T: lane holds S[key=nt*16+quad*4+r][q=qrow] ----
        f32x4 sc[4];
        float pm = MASKV;
#pragma unroll
        for (int nt = 0; nt < 4; nt++) {
          if ((kt * 64 + nt * 16) <= (qbase + 15)) { // wave-uniform skip
            const int krow = (nt * 16 + m) * 64;
            const bf16x8 k0 =
                *(const bf16x8*)&Kc[krow + ((quad ^ (m & 7)) & 7) * 8];
            const bf16x8 k1 =
                *(const bf16x8*)&Kc[krow + (((quad + 4) ^ (m & 7)) & 7) * 8];
            f32x4 c = (f32x4){0.f, 0.f, 0.f, 0.f};
            c = MFMA16(k0, qf0, c);     // SWAPPED: A=K (row=key), B=Q (col=q)
            c = MFMA16(k1, qf1, c);
            const unsigned w32 = (nt < 2) ? kqlo : kqhi;
#pragma unroll
            for (int r = 0; r < 4; r++) {
              const int sh = (nt & 1) * 16 + r;      // compile-time
              const float s = ((w32 >> sh) & 1u) ? c[r] * 0.125f : MASKV;
              sc[nt][r] = s;
              pm = fmaxf(pm, s);
            }
          } else {
#pragma unroll
            for (int r = 0; r < 4; r++) sc[nt][r] = MASKV;
          }
        }
        // cross-lane max over the 4 key-subsets of this row
        pm = fmaxf(pm, __shfl_xor(pm, 16));
        pm = fmaxf(pm, __shfl_xor(pm, 32));

        // ---- defer-max: rescale only when some row grew past THR=8 ----
        if (__any(pm > mi + 8.0f)) {
          const float mn = (pm > mi + 8.0f) ? pm : mi;
          const float alpha = exp2f((mi - mn) * L2E);
          mi = mn;
          li *= alpha;
#pragma unroll
          for (int r = 0; r < 4; r++) {
            const float ar = __shfl(alpha, quad * 4 + r);
#pragma unroll
            for (int ot = 0; ot < 4; ot++) o[ot][r] *= ar;
          }
        }

        // ---- P = exp2(sc - mi); pack via cvt_pk; 4x ds_write_b64 ----
        float rsum = 0.f;
#pragma unroll
        for (int nt = 0; nt < 4; nt++) {
          float pf[4];
#pragma unroll
          for (int r = 0; r < 4; r++) {
            pf[r] = exp2f((sc[nt][r] - mi) * L2E);  // masked -> 0
            rsum += pf[r];
          }
          unsigned w0, w1;
          asm("v_cvt_pk_bf16_f32 %0, %1, %2" : "=v"(w0) : "v"(pf[0]), "v"(pf[1]));
          asm("v_cvt_pk_bf16_f32 %0, %1, %2" : "=v"(w1) : "v"(pf[2]), "v"(pf[3]));
          uint2 wv; wv.x = w0; wv.y = w1;
          *(uint2*)&Pw[m * PSTR + nt * 16 + quad * 4] = wv;
        }
        rsum += __shfl_xor(rsum, 16);
        rsum += __shfl_xor(rsum, 32);
        li += rsum;

        // ---- P @ V (P rows=q via per-wave LDS; V from staged LDS) ----
        const bf16x8 p0 = *(const bf16x8*)&Pw[m * PSTR + quad * 8];
        const bf16x8 p1 = *(const bf16x8*)&Pw[m * PSTR + 32 + quad * 8];
#pragma unroll
        for (int ot = 0; ot < 4; ot++) {
          const int vrow = (ot * 16 + m) * 64;
          const bf16x8 v0 =
              *(const bf16x8*)&Vc[vrow + ((quad ^ (m & 7)) & 7) * 8];
          const bf16x8 v1 =
              *(const bf16x8*)&Vc[vrow + (((quad + 4) ^ (m & 7)) & 7) * 8];
          o[ot] = MFMA16(p0, v0, o[ot]);
          o[ot] = MFMA16(p1, v1, o[ot]);
        }
      }

      __syncthreads();  // next tile staged + all reads of cur tile complete
    }

    // ---- epilogue: o rows = q = qbase+quad*4+r; li lives at lane q&15 ----
    const float linv = (li > 1e-30f) ? 1.f / li : 0.f;
#pragma unroll
    for (int r = 0; r < 4; r++) {
      const float inv = __shfl(linv, quad * 4 + r);
      const int qo = qbase + quad * 4 + r;
#pragma unroll
      for (int ot = 0; ot < 4; ot++) {
        const int col = h * 64 + ot * 16 + m;
        Oo[((size_t)(b * 1024 + qo)) * 1024 + col] = f2b(o[ot][r] * inv);
      }
    }
  }
}

// ---------------------------------------------------------------------------
extern "C" void kernel_launch(void* const* d_in, const int* in_sizes, int n_in,
                              void* d_out, int out_size, void* d_ws, size_t ws_size,
                              hipStream_t stream) {
  const float* x  = (const float*)d_in[0];
  const int*   ids = (const int*)d_in[1];
  const float* Wq = (const float*)d_in[2];
  const float* bq = (const float*)d_in[3];
  const float* Wk = (const float*)d_in[4];
  const float* bk = (const float*)d_in[5];
  const float* Wv = (const float*)d_in[6];
  const float* bv = (const float*)d_in[7];
  const float* Wo = (const float*)d_in[8];
  const float* bo = (const float*)d_in[9];
  float* out = (float*)d_out;

  // ws layout (bf16 elems): XB 8.4M | WqB,WkB,WvB,WoB 1M each | Q,K,V 8.4M each
  u16t* XB  = (u16t*)d_ws;
  u16t* WqB = XB  + 8388608;
  u16t* WkB = WqB + 1048576;
  u16t* WvB = WkB + 1048576;
  u16t* WoB = WvB + 1048576;
  u16t* Qw  = WoB + 1048576;
  u16t* Kw  = Qw  + 8388608;
  u16t* Vw  = Kw  + 8388608;   // holds V^T[b][h][hd][s]
  u16t* AO  = XB; // reuse after gemm_qkv consumed XB

  cvt5<<<6144, 256, 0, stream>>>(x, Wq, Wk, Wv, Wo, XB, WqB, WkB, WvB, WoB);
  gemm_qkv<<<dim3(8, 64, 3), 256, 0, stream>>>(XB, WqB, WkB, WvB, bq, bk, bv,
                                               Qw, Kw, Vw);
  attn<<<512, 512, 0, stream>>>(Qw, Kw, Vw, ids, AO);
  gemm_o<<<dim3(8, 64, 1), 256, 0, stream>>>(AO, WoB, bo, out);
}

// Round 10
// 254.337 us; speedup vs baseline: 1.4385x; 1.0429x over previous
//
#include <hip/hip_runtime.h>

typedef __attribute__((ext_vector_type(8))) short bf16x8;
typedef __attribute__((ext_vector_type(8))) unsigned short u16x8;
typedef __attribute__((ext_vector_type(4))) unsigned short u16x4;
typedef __attribute__((ext_vector_type(4))) float f32x4;
typedef unsigned short u16t;

#define MFMA16(a, b, c) __builtin_amdgcn_mfma_f32_16x16x32_bf16((a), (b), (c), 0, 0, 0)
#define GLDS16(gp, lp)                                                        \
  __builtin_amdgcn_global_load_lds(                                           \
      (__attribute__((address_space(1))) void*)(gp),                          \
      (__attribute__((address_space(3))) void*)(lp), 16, 0, 0)

static constexpr float L2E = 1.44269504f;   // log2(e)
static constexpr float MASKV = -1.0e30f;    // finite mask sentinel (no inf paths)

__device__ __forceinline__ u16t f2b(float f) {
  unsigned u = __builtin_bit_cast(unsigned, f);
  u = u + 0x7fffu + ((u >> 16) & 1u); // RNE
  return (u16t)(u >> 16);
}

// ---------------------------------------------------------------------------
// fp32 -> bf16 conversion of x and the 4 weight matrices, one fused launch.
// ---------------------------------------------------------------------------
__global__ void cvt5(const float* __restrict__ x, const float* __restrict__ wq,
                     const float* __restrict__ wk, const float* __restrict__ wv,
                     const float* __restrict__ wo, u16t* __restrict__ xb,
                     u16t* __restrict__ wqb, u16t* __restrict__ wkb,
                     u16t* __restrict__ wvb, u16t* __restrict__ wob) {
  const int bid = blockIdx.x;
  const float* src; u16t* dst; int gb;
  if (bid < 4096)      { src = x;  dst = xb;  gb = bid; }
  else if (bid < 4608) { src = wq; dst = wqb; gb = bid - 4096; }
  else if (bid < 5120) { src = wk; dst = wkb; gb = bid - 4608; }
  else if (bid < 5632) { src = wv; dst = wvb; gb = bid - 5120; }
  else                 { src = wo; dst = wob; gb = bid - 5632; }
  const size_t i = (size_t)gb * 256 + threadIdx.x; // 8-elem group index
  const float4 a = ((const float4*)src)[2 * i];
  const float4 b = ((const float4*)src)[2 * i + 1];
  u16x8 r;
  r[0] = f2b(a.x); r[1] = f2b(a.y); r[2] = f2b(a.z); r[3] = f2b(a.w);
  r[4] = f2b(b.x); r[5] = f2b(b.y); r[6] = f2b(b.z); r[7] = f2b(b.w);
  *(u16x8*)&dst[8 * i] = r;
}

// ---------------------------------------------------------------------------
// GEMM v10: m97 fragment layout + DOUBLE-BUFFERED LDS with prefetch-before-
// compute (one barrier/iter; the attn-v9 pattern -- the old stage->sync
// structure exposed full global latency every K-step: MfmaUtil 19%) and
// XCD-AFFINE decode (id&7 = XCD owns by-slice; all 24 (bx,z) blocks sharing
// an X row-panel are consecutive on one XCD -> X fetched once from HBM).
// z=2 (V) writes transposed V^T[b][h][hd][s] for the attention PV step.
// ---------------------------------------------------------------------------
__global__ void gemm_qkv(const u16t* __restrict__ X,
                         const u16t* __restrict__ Wq, const u16t* __restrict__ Wk,
                         const u16t* __restrict__ Wv,
                         const float* __restrict__ bq, const float* __restrict__ bk,
                         const float* __restrict__ bv,
                         u16t* __restrict__ Qo, u16t* __restrict__ Ko,
                         u16t* __restrict__ Vo) {
  __shared__ __align__(16) u16t As[2][128 * 32];
  __shared__ __align__(16) u16t Bs[2][128 * 32];
  const int t = threadIdx.x, lane = t & 63, w = t >> 6;
  const int wr = w >> 1, wc = w & 1, m = lane & 15, quad = lane >> 4;
  // XCD-affine decode: xcd = id&7; by = xcd*8 + (j&7); bx = rem&7; z = rem>>3
  const int id = blockIdx.x;
  const int xcd = id & 7, j = id >> 3;
  const int by = xcd * 8 + (j & 7);
  const int rem = j >> 3;                // 0..23
  const int bx = rem & 7, z = rem >> 3;  // bx 0..7, z 0..2
  const int rowBase = by * 128, colBase = bx * 128;
  const u16t* W = (z == 0) ? Wq : ((z == 1) ? Wk : Wv);
  const float* bias = (z == 0) ? bq : ((z == 1) ? bk : bv);
  u16t* Out = (z == 0) ? Qo : ((z == 1) ? Ko : Vo);

  f32x4 acc[4][4];
#pragma unroll
  for (int i = 0; i < 4; i++)
#pragma unroll
    for (int j2 = 0; j2 < 4; j2++) acc[i][j2] = (f32x4){0.f, 0.f, 0.f, 0.f};

  const int lr = lane >> 2, lc = (lane & 3) * 8;
  // prologue: stage kt=0 into buffer 0
#pragma unroll
  for (int i = 0; i < 2; ++i) {
    const int r0 = i * 64 + w * 16;
    GLDS16(&X[(size_t)(rowBase + r0 + lr) * 1024 + lc], &As[0][r0 * 32]);
    GLDS16(&W[(size_t)(colBase + r0 + lr) * 1024 + lc], &Bs[0][r0 * 32]);
  }
  __syncthreads();

  for (int kt = 0; kt < 32; ++kt) {
    const int cur = kt & 1;
    if (kt < 31) {  // prefetch kt+1 into the other buffer (drained at barrier)
#pragma unroll
      for (int i = 0; i < 2; ++i) {
        const int r0 = i * 64 + w * 16;
        GLDS16(&X[(size_t)(rowBase + r0 + lr) * 1024 + (kt + 1) * 32 + lc],
               &As[cur ^ 1][r0 * 32]);
        GLDS16(&W[(size_t)(colBase + r0 + lr) * 1024 + (kt + 1) * 32 + lc],
               &Bs[cur ^ 1][r0 * 32]);
      }
    }
    bf16x8 af[4], bfr[4];
#pragma unroll
    for (int i = 0; i < 4; i++)
      af[i] = *(const bf16x8*)&As[cur][(wr * 64 + i * 16 + m) * 32 + quad * 8];
#pragma unroll
    for (int j2 = 0; j2 < 4; j2++)
      bfr[j2] = *(const bf16x8*)&Bs[cur][(wc * 64 + j2 * 16 + m) * 32 + quad * 8];
#pragma unroll
    for (int i = 0; i < 4; i++)
#pragma unroll
      for (int j2 = 0; j2 < 4; j2++) acc[i][j2] = MFMA16(af[i], bfr[j2], acc[i][j2]);
    __syncthreads();  // prefetch landed + all reads of cur complete
  }

  const int b_ = rowBase >> 10;          // whole block is in one batch row
  const int sBase = (rowBase & 1023) + wr * 64;
#pragma unroll
  for (int j2 = 0; j2 < 4; j2++) {
    const int col = colBase + wc * 64 + j2 * 16 + m;
    const float bv_ = bias[col];
    const int h = col >> 6, hd = col & 63;
    if (z == 2) {
      // V^T: Out[((b*16+h)*64 + hd)*1024 + s], 4 consecutive s per u16x4
#pragma unroll
      for (int i = 0; i < 4; i++) {
        const int s0 = sBase + i * 16 + quad * 4;
        u16x4 pk;
#pragma unroll
        for (int r = 0; r < 4; r++) pk[r] = f2b(acc[i][j2][r] + bv_);
        *(u16x4*)&Out[(((size_t)b_ * 16 + h) * 64 + hd) * 1024 + s0] = pk;
      }
    } else {
#pragma unroll
      for (int i = 0; i < 4; i++) {
#pragma unroll
        for (int r = 0; r < 4; r++) {
          const int s_ = sBase + i * 16 + quad * 4 + r;
          const size_t oi = (((size_t)b_ * 16 + h) * 1024 + s_) * 64 + hd;
          Out[oi] = f2b(acc[i][j2][r] + bv_);
        }
      }
    }
  }
}

__global__ void gemm_o(const u16t* __restrict__ A, const u16t* __restrict__ W,
                       const float* __restrict__ bias, float* __restrict__ Out) {
  __shared__ __align__(16) u16t As[2][128 * 32];
  __shared__ __align__(16) u16t Bs[2][128 * 32];
  const int t = threadIdx.x, lane = t & 63, w = t >> 6;
  const int wr = w >> 1, wc = w & 1, m = lane & 15, quad = lane >> 4;
  // XCD-affine decode: 512 blocks; by = (id&7)*8 + (j&7); bx = j>>3
  const int id = blockIdx.x;
  const int xcd = id & 7, j = id >> 3;
  const int by = xcd * 8 + (j & 7);
  const int bx = j >> 3;                 // 0..7
  const int rowBase = by * 128, colBase = bx * 128;

  f32x4 acc[4][4];
#pragma unroll
  for (int i = 0; i < 4; i++)
#pragma unroll
    for (int j2 = 0; j2 < 4; j2++) acc[i][j2] = (f32x4){0.f, 0.f, 0.f, 0.f};

  const int lr = lane >> 2, lc = (lane & 3) * 8;
#pragma unroll
  for (int i = 0; i < 2; ++i) {
    const int r0 = i * 64 + w * 16;
    GLDS16(&A[(size_t)(rowBase + r0 + lr) * 1024 + lc], &As[0][r0 * 32]);
    GLDS16(&W[(size_t)(colBase + r0 + lr) * 1024 + lc], &Bs[0][r0 * 32]);
  }
  __syncthreads();

  for (int kt = 0; kt < 32; ++kt) {
    const int cur = kt & 1;
    if (kt < 31) {
#pragma unroll
      for (int i = 0; i < 2; ++i) {
        const int r0 = i * 64 + w * 16;
        GLDS16(&A[(size_t)(rowBase + r0 + lr) * 1024 + (kt + 1) * 32 + lc],
               &As[cur ^ 1][r0 * 32]);
        GLDS16(&W[(size_t)(colBase + r0 + lr) * 1024 + (kt + 1) * 32 + lc],
               &Bs[cur ^ 1][r0 * 32]);
      }
    }
    bf16x8 af[4], bfr[4];
#pragma unroll
    for (int i = 0; i < 4; i++)
      af[i] = *(const bf16x8*)&As[cur][(wr * 64 + i * 16 + m) * 32 + quad * 8];
#pragma unroll
    for (int j2 = 0; j2 < 4; j2++)
      bfr[j2] = *(const bf16x8*)&Bs[cur][(wc * 64 + j2 * 16 + m) * 32 + quad * 8];
#pragma unroll
    for (int i = 0; i < 4; i++)
#pragma unroll
      for (int j2 = 0; j2 < 4; j2++) acc[i][j2] = MFMA16(af[i], bfr[j2], acc[i][j2]);
    __syncthreads();
  }

#pragma unroll
  for (int j2 = 0; j2 < 4; j2++) {
    const int col = colBase + wc * 64 + j2 * 16 + m;
    const float bv_ = bias[col];
#pragma unroll
    for (int i = 0; i < 4; i++) {
#pragma unroll
      for (int r = 0; r < 4; r++) {
        const int row = rowBase + wr * 64 + i * 16 + quad * 4 + r;
        Out[(size_t)row * 1024 + col] = acc[i][j2][r] + bv_;
      }
    }
  }
}

// ---------------------------------------------------------------------------
// Flash attention v9 (unchanged -- passed round 9, <106us):
// block-cooperative LDS staging of K/V^T (8 waves share), double-buffered
// with prefetch-before-compute; swapped QK^T -> per-lane scalar online
// softmax; defer-max THR=8; cvt_pk P-pack; XOR-granule swizzled staging.
// ---------------------------------------------------------------------------
__global__ __launch_bounds__(512) void attn(
    const u16t* __restrict__ Q, const u16t* __restrict__ K,
    const u16t* __restrict__ VT, const int* __restrict__ ids,
    u16t* __restrict__ Oo) {
  constexpr int PSTR = 72;
  __shared__ __align__(16) u16t Kb[2][64 * 64];
  __shared__ __align__(16) u16t Vb[2][64 * 64];
  __shared__ __align__(16) u16t Ps[8][16 * PSTR];
  __shared__ unsigned long long maskL[16];

  const int t = threadIdx.x, lane = t & 63, wl = t >> 6;  // wl: 0..7
  const int m = lane & 15, quad = lane >> 4;
  const int id = blockIdx.x;
  const int g = id & 7, k_ = id >> 3;
  const int bh = g + 8 * (k_ & 15);
  const int p4 = k_ >> 4;                // 0..3
  const int b = bh >> 4, h = bh & 15;
  const size_t hoff = (size_t)bh * 65536;   // 1024 * 64

  const int srow = lane >> 3;
  const int sg = (lane & 7) ^ (srow & 7);

#pragma unroll
  for (int c = 0; c < 2; ++c) {
    const int chunk = wl * 2 + c;
    const int idv = ids[b * 1024 + chunk * 64 + lane];
    const unsigned long long mk = __ballot(idv != 1);
    if (lane == 0) maskL[chunk] = mk;
  }
  __syncthreads();

  u16t* const Pw = &Ps[wl][0];

  for (int pass = 0; pass < 2; ++pass) {
    const int qt8 = pass ? (7 - p4) : p4;
    const int qbase = qt8 * 128 + wl * 16;
    const int qrow = qbase + m;          // this lane's softmax row
    const int ktmax = 2 * qt8 + 1;

    GLDS16(&K[hoff + (size_t)(wl * 8 + srow) * 64 + sg * 8], &Kb[0][wl * 512]);
    GLDS16(&VT[hoff + (size_t)(wl * 8 + srow) * 1024 + sg * 8], &Vb[0][wl * 512]);

    const bf16x8 qf0 =
        *(const bf16x8*)&Q[hoff + (size_t)(qbase + m) * 64 + quad * 8];
    const bf16x8 qf1 =
        *(const bf16x8*)&Q[hoff + (size_t)(qbase + m) * 64 + 32 + quad * 8];

    float mi = MASKV, li = 0.f;
    f32x4 o[4];
#pragma unroll
    for (int ot = 0; ot < 4; ot++) o[ot] = (f32x4){0.f, 0.f, 0.f, 0.f};

    __syncthreads();   // buf0 staged (drains vmcnt)

    for (int kt = 0; kt <= ktmax; ++kt) {
      if (kt < ktmax) {
        u16t* const kb = &Kb[(kt + 1) & 1][wl * 512];
        u16t* const vb = &Vb[(kt + 1) & 1][wl * 512];
        GLDS16(&K[hoff + (size_t)((kt + 1) * 64 + wl * 8 + srow) * 64 + sg * 8], kb);
        GLDS16(&VT[hoff + (size_t)(wl * 8 + srow) * 1024 + (kt + 1) * 64 + sg * 8], vb);
      }

      if (kt * 64 <= qbase + 15) {       // wave-uniform: any causal work?
        const u16t* const Kc = Kb[kt & 1];
        const u16t* const Vc = Vb[kt & 1];

        const int dq0 = qrow - kt * 64;            // >= 0 inside guard
        const int dqc = dq0 > 63 ? 63 : dq0;
        const unsigned long long causal =
            (dqc == 63) ? ~0ull : ((1ull << (dqc + 1)) - 1ull);
        const unsigned long long km2 = maskL[kt] & causal;
        const unsigned kqlo = (unsigned)(km2 >> (quad * 4));
        const unsigned kqhi = (unsigned)(km2 >> (quad * 4 + 32));

        f32x4 sc[4];
        float pm = MASKV;
#pragma unroll
        for (int nt = 0; nt < 4; nt++) {
          if ((kt * 64 + nt * 16) <= (qbase + 15)) { // wave-uniform skip
            const int krow = (nt * 16 + m) * 64;
            const bf16x8 k0 =
                *(const bf16x8*)&Kc[krow + ((quad ^ (m & 7)) & 7) * 8];
            const bf16x8 k1 =
                *(const bf16x8*)&Kc[krow + (((quad + 4) ^ (m & 7)) & 7) * 8];
            f32x4 c = (f32x4){0.f, 0.f, 0.f, 0.f};
            c = MFMA16(k0, qf0, c);     // SWAPPED: A=K (row=key), B=Q (col=q)
            c = MFMA16(k1, qf1, c);
            const unsigned w32 = (nt < 2) ? kqlo : kqhi;
#pragma unroll
            for (int r = 0; r < 4; r++) {
              const int sh = (nt & 1) * 16 + r;      // compile-time
              const float s = ((w32 >> sh) & 1u) ? c[r] * 0.125f : MASKV;
              sc[nt][r] = s;
              pm = fmaxf(pm, s);
            }
          } else {
#pragma unroll
            for (int r = 0; r < 4; r++) sc[nt][r] = MASKV;
          }
        }
        pm = fmaxf(pm, __shfl_xor(pm, 16));
        pm = fmaxf(pm, __shfl_xor(pm, 32));

        if (__any(pm > mi + 8.0f)) {
          const float mn = (pm > mi + 8.0f) ? pm : mi;
          const float alpha = exp2f((mi - mn) * L2E);
          mi = mn;
          li *= alpha;
#pragma unroll
          for (int r = 0; r < 4; r++) {
            const float ar = __shfl(alpha, quad * 4 + r);
#pragma unroll
            for (int ot = 0; ot < 4; ot++) o[ot][r] *= ar;
          }
        }

        float rsum = 0.f;
#pragma unroll
        for (int nt = 0; nt < 4; nt++) {
          float pf[4];
#pragma unroll
          for (int r = 0; r < 4; r++) {
            pf[r] = exp2f((sc[nt][r] - mi) * L2E);  // masked -> 0
            rsum += pf[r];
          }
          unsigned w0, w1;
          asm("v_cvt_pk_bf16_f32 %0, %1, %2" : "=v"(w0) : "v"(pf[0]), "v"(pf[1]));
          asm("v_cvt_pk_bf16_f32 %0, %1, %2" : "=v"(w1) : "v"(pf[2]), "v"(pf[3]));
          uint2 wv; wv.x = w0; wv.y = w1;
          *(uint2*)&Pw[m * PSTR + nt * 16 + quad * 4] = wv;
        }
        rsum += __shfl_xor(rsum, 16);
        rsum += __shfl_xor(rsum, 32);
        li += rsum;

        const bf16x8 p0 = *(const bf16x8*)&Pw[m * PSTR + quad * 8];
        const bf16x8 p1 = *(const bf16x8*)&Pw[m * PSTR + 32 + quad * 8];
#pragma unroll
        for (int ot = 0; ot < 4; ot++) {
          const int vrow = (ot * 16 + m) * 64;
          const bf16x8 v0 =
              *(const bf16x8*)&Vc[vrow + ((quad ^ (m & 7)) & 7) * 8];
          const bf16x8 v1 =
              *(const bf16x8*)&Vc[vrow + (((quad + 4) ^ (m & 7)) & 7) * 8];
          o[ot] = MFMA16(p0, v0, o[ot]);
          o[ot] = MFMA16(p1, v1, o[ot]);
        }
      }

      __syncthreads();  // next tile staged + all reads of cur tile complete
    }

    const float linv = (li > 1e-30f) ? 1.f / li : 0.f;
#pragma unroll
    for (int r = 0; r < 4; r++) {
      const float inv = __shfl(linv, quad * 4 + r);
      const int qo = qbase + quad * 4 + r;
#pragma unroll
      for (int ot = 0; ot < 4; ot++) {
        const int col = h * 64 + ot * 16 + m;
        Oo[((size_t)(b * 1024 + qo)) * 1024 + col] = f2b(o[ot][r] * inv);
      }
    }
  }
}

// ---------------------------------------------------------------------------
extern "C" void kernel_launch(void* const* d_in, const int* in_sizes, int n_in,
                              void* d_out, int out_size, void* d_ws, size_t ws_size,
                              hipStream_t stream) {
  const float* x  = (const float*)d_in[0];
  const int*   ids = (const int*)d_in[1];
  const float* Wq = (const float*)d_in[2];
  const float* bq = (const float*)d_in[3];
  const float* Wk = (const float*)d_in[4];
  const float* bk = (const float*)d_in[5];
  const float* Wv = (const float*)d_in[6];
  const float* bv = (const float*)d_in[7];
  const float* Wo = (const float*)d_in[8];
  const float* bo = (const float*)d_in[9];
  float* out = (float*)d_out;

  // ws layout (bf16 elems): XB 8.4M | WqB,WkB,WvB,WoB 1M each | Q,K,V 8.4M each
  u16t* XB  = (u16t*)d_ws;
  u16t* WqB = XB  + 8388608;
  u16t* WkB = WqB + 1048576;
  u16t* WvB = WkB + 1048576;
  u16t* WoB = WvB + 1048576;
  u16t* Qw  = WoB + 1048576;
  u16t* Kw  = Qw  + 8388608;
  u16t* Vw  = Kw  + 8388608;   // holds V^T[b][h][hd][s]
  u16t* AO  = XB; // reuse after gemm_qkv consumed XB

  cvt5<<<6144, 256, 0, stream>>>(x, Wq, Wk, Wv, Wo, XB, WqB, WkB, WvB, WoB);
  gemm_qkv<<<1536, 256, 0, stream>>>(XB, WqB, WkB, WvB, bq, bk, bv, Qw, Kw, Vw);
  attn<<<512, 512, 0, stream>>>(Qw, Kw, Vw, ids, AO);
  gemm_o<<<512, 256, 0, stream>>>(AO, WoB, bo, out);
}

// Round 11
// 242.179 us; speedup vs baseline: 1.5107x; 1.0502x over previous
//
#include <hip/hip_runtime.h>

typedef __attribute__((ext_vector_type(8))) short bf16x8;
typedef __attribute__((ext_vector_type(8))) unsigned short u16x8;
typedef __attribute__((ext_vector_type(4))) unsigned short u16x4;
typedef __attribute__((ext_vector_type(4))) float f32x4;
typedef unsigned short u16t;

#define MFMA16(a, b, c) __builtin_amdgcn_mfma_f32_16x16x32_bf16((a), (b), (c), 0, 0, 0)
#define GLDS16(gp, lp)                                                        \
  __builtin_amdgcn_global_load_lds(                                           \
      (__attribute__((address_space(1))) void*)(gp),                          \
      (__attribute__((address_space(3))) void*)(lp), 16, 0, 0)

static constexpr float L2E = 1.44269504f;   // log2(e)
static constexpr float MASKV = -1.0e30f;    // finite mask sentinel (no inf paths)

__device__ __forceinline__ u16t f2b(float f) {
  unsigned u = __builtin_bit_cast(unsigned, f);
  u = u + 0x7fffu + ((u >> 16) & 1u); // RNE
  return (u16t)(u >> 16);
}

// ---------------------------------------------------------------------------
// fp32 -> bf16 conversion of x and the 4 weight matrices, one fused launch.
// ---------------------------------------------------------------------------
__global__ void cvt5(const float* __restrict__ x, const float* __restrict__ wq,
                     const float* __restrict__ wk, const float* __restrict__ wv,
                     const float* __restrict__ wo, u16t* __restrict__ xb,
                     u16t* __restrict__ wqb, u16t* __restrict__ wkb,
                     u16t* __restrict__ wvb, u16t* __restrict__ wob) {
  const int bid = blockIdx.x;
  const float* src; u16t* dst; int gb;
  if (bid < 4096)      { src = x;  dst = xb;  gb = bid; }
  else if (bid < 4608) { src = wq; dst = wqb; gb = bid - 4096; }
  else if (bid < 5120) { src = wk; dst = wkb; gb = bid - 4608; }
  else if (bid < 5632) { src = wv; dst = wvb; gb = bid - 5120; }
  else                 { src = wo; dst = wob; gb = bid - 5632; }
  const size_t i = (size_t)gb * 256 + threadIdx.x; // 8-elem group index
  const float4 a = ((const float4*)src)[2 * i];
  const float4 b = ((const float4*)src)[2 * i + 1];
  u16x8 r;
  r[0] = f2b(a.x); r[1] = f2b(a.y); r[2] = f2b(a.z); r[3] = f2b(a.w);
  r[4] = f2b(b.x); r[5] = f2b(b.y); r[6] = f2b(b.z); r[7] = f2b(b.w);
  *(u16x8*)&dst[8 * i] = r;
}

// ---------------------------------------------------------------------------
// GEMM v11 (qkv): dbuf + XCD-affine (r10, passed) with two changes:
//  1. 48KB LDS (SMEM block) forces 3 blocks/CU -> 1536/(256*3) = 2.0 UNIFORM
//     rounds (r10: reg-limited 4/CU gave 1.5 ragged rounds = the 655-vs-870TF
//     gap; MfmaUtil 26.8% matched tail arithmetic exactly).
//  2. Q/K epilogue: acc -> bf16 LDS tile (stride 136, de-banked) -> 8x
//     coalesced u16x8 stores/thread (was 64 scalar 2B scatter-stores, 74MB
//     WRITE_SIZE). V^T epilogue (already u16x4-vectorized) unchanged.
// ---------------------------------------------------------------------------
__global__ void gemm_qkv(const u16t* __restrict__ X,
                         const u16t* __restrict__ Wq, const u16t* __restrict__ Wk,
                         const u16t* __restrict__ Wv,
                         const float* __restrict__ bq, const float* __restrict__ bk,
                         const float* __restrict__ bv,
                         u16t* __restrict__ Qo, u16t* __restrict__ Ko,
                         u16t* __restrict__ Vo) {
  // 48KB shared: As dbuf 16KB | Bs dbuf 16KB | epilogue reuses from offset 0
  __shared__ __align__(16) u16t SMEM[24576];
  u16t* const As = SMEM;           // [2][128*32]
  u16t* const Bs = SMEM + 8192;    // [2][128*32]
  u16t* const Et = SMEM;           // epilogue tile [128][136] (17408 <= 24576)

  const int t = threadIdx.x, lane = t & 63, w = t >> 6;
  const int wr = w >> 1, wc = w & 1, m = lane & 15, quad = lane >> 4;
  // XCD-affine decode: xcd = id&7; by = xcd*8 + (j&7); bx = rem&7; z = rem>>3
  const int id = blockIdx.x;
  const int xcd = id & 7, j = id >> 3;
  const int by = xcd * 8 + (j & 7);
  const int rem = j >> 3;                // 0..23
  const int bx = rem & 7, z = rem >> 3;  // bx 0..7, z 0..2
  const int rowBase = by * 128, colBase = bx * 128;
  const u16t* W = (z == 0) ? Wq : ((z == 1) ? Wk : Wv);
  const float* bias = (z == 0) ? bq : ((z == 1) ? bk : bv);
  u16t* Out = (z == 0) ? Qo : ((z == 1) ? Ko : Vo);

  f32x4 acc[4][4];
#pragma unroll
  for (int i = 0; i < 4; i++)
#pragma unroll
    for (int j2 = 0; j2 < 4; j2++) acc[i][j2] = (f32x4){0.f, 0.f, 0.f, 0.f};

  const int lr = lane >> 2, lc = (lane & 3) * 8;
  // prologue: stage kt=0 into buffer 0
#pragma unroll
  for (int i = 0; i < 2; ++i) {
    const int r0 = i * 64 + w * 16;
    GLDS16(&X[(size_t)(rowBase + r0 + lr) * 1024 + lc], &As[r0 * 32]);
    GLDS16(&W[(size_t)(colBase + r0 + lr) * 1024 + lc], &Bs[r0 * 32]);
  }
  __syncthreads();

  for (int kt = 0; kt < 32; ++kt) {
    const int cur = kt & 1;
    if (kt < 31) {  // prefetch kt+1 into the other buffer (drained at barrier)
#pragma unroll
      for (int i = 0; i < 2; ++i) {
        const int r0 = i * 64 + w * 16;
        GLDS16(&X[(size_t)(rowBase + r0 + lr) * 1024 + (kt + 1) * 32 + lc],
               &As[(cur ^ 1) * 4096 + r0 * 32]);
        GLDS16(&W[(size_t)(colBase + r0 + lr) * 1024 + (kt + 1) * 32 + lc],
               &Bs[(cur ^ 1) * 4096 + r0 * 32]);
      }
    }
    bf16x8 af[4], bfr[4];
#pragma unroll
    for (int i = 0; i < 4; i++)
      af[i] = *(const bf16x8*)&As[cur * 4096 + (wr * 64 + i * 16 + m) * 32 + quad * 8];
#pragma unroll
    for (int j2 = 0; j2 < 4; j2++)
      bfr[j2] = *(const bf16x8*)&Bs[cur * 4096 + (wc * 64 + j2 * 16 + m) * 32 + quad * 8];
#pragma unroll
    for (int i = 0; i < 4; i++)
#pragma unroll
      for (int j2 = 0; j2 < 4; j2++) acc[i][j2] = MFMA16(af[i], bfr[j2], acc[i][j2]);
    __syncthreads();  // prefetch landed + all reads of cur complete
  }

  const int b_ = rowBase >> 10;          // whole block is in one batch row
  const int sBase0 = rowBase & 1023;
  if (z == 2) {
    // V^T: Out[((b*16+h)*64 + hd)*1024 + s], 4 consecutive s per u16x4
    const int sBase = sBase0 + wr * 64;
#pragma unroll
    for (int j2 = 0; j2 < 4; j2++) {
      const int col = colBase + wc * 64 + j2 * 16 + m;
      const float bv_ = bias[col];
      const int h = col >> 6, hd = col & 63;
#pragma unroll
      for (int i = 0; i < 4; i++) {
        const int s0 = sBase + i * 16 + quad * 4;
        u16x4 pk;
#pragma unroll
        for (int r = 0; r < 4; r++) pk[r] = f2b(acc[i][j2][r] + bv_);
        *(u16x4*)&Out[(((size_t)b_ * 16 + h) * 64 + hd) * 1024 + s0] = pk;
      }
    }
  } else {
    // Q/K: stage bf16 into Et[128][136], then coalesced u16x8 row stores
    constexpr int ESTR = 136;            // 272B rows: 16B-aligned, de-banked
#pragma unroll
    for (int j2 = 0; j2 < 4; j2++) {
      const int cl = wc * 64 + j2 * 16 + m;
      const float bv_ = bias[colBase + cl];
#pragma unroll
      for (int i = 0; i < 4; i++)
#pragma unroll
        for (int r = 0; r < 4; r++)
          Et[(wr * 64 + i * 16 + quad * 4 + r) * ESTR + cl] =
              f2b(acc[i][j2][r] + bv_);
    }
    __syncthreads();
    const int hbase = colBase >> 6;      // two heads: hbase, hbase+1
#pragma unroll
    for (int it = 0; it < 8; ++it) {
      const int chunk = it * 256 + t;    // 2048 16B-chunks = 128 rows x 16
      const int sl = chunk >> 4, c8 = chunk & 15;
      const u16x8 v = *(const u16x8*)&Et[sl * ESTR + c8 * 8];
      const int h2 = hbase + (c8 >> 3), hd0 = (c8 & 7) * 8;
      *(u16x8*)&Out[(((size_t)b_ * 16 + h2) * 1024 + (sBase0 + sl)) * 64 + hd0] = v;
    }
  }
}

__global__ void gemm_o(const u16t* __restrict__ A, const u16t* __restrict__ W,
                       const float* __restrict__ bias, float* __restrict__ Out) {
  __shared__ __align__(16) u16t As[2][128 * 32];
  __shared__ __align__(16) u16t Bs[2][128 * 32];
  const int t = threadIdx.x, lane = t & 63, w = t >> 6;
  const int wr = w >> 1, wc = w & 1, m = lane & 15, quad = lane >> 4;
  // XCD-affine decode: 512 blocks; by = (id&7)*8 + (j&7); bx = j>>3
  const int id = blockIdx.x;
  const int xcd = id & 7, j = id >> 3;
  const int by = xcd * 8 + (j & 7);
  const int bx = j >> 3;                 // 0..7
  const int rowBase = by * 128, colBase = bx * 128;

  f32x4 acc[4][4];
#pragma unroll
  for (int i = 0; i < 4; i++)
#pragma unroll
    for (int j2 = 0; j2 < 4; j2++) acc[i][j2] = (f32x4){0.f, 0.f, 0.f, 0.f};

  const int lr = lane >> 2, lc = (lane & 3) * 8;
#pragma unroll
  for (int i = 0; i < 2; ++i) {
    const int r0 = i * 64 + w * 16;
    GLDS16(&A[(size_t)(rowBase + r0 + lr) * 1024 + lc], &As[0][r0 * 32]);
    GLDS16(&W[(size_t)(colBase + r0 + lr) * 1024 + lc], &Bs[0][r0 * 32]);
  }
  __syncthreads();

  for (int kt = 0; kt < 32; ++kt) {
    const int cur = kt & 1;
    if (kt < 31) {
#pragma unroll
      for (int i = 0; i < 2; ++i) {
        const int r0 = i * 64 + w * 16;
        GLDS16(&A[(size_t)(rowBase + r0 + lr) * 1024 + (kt + 1) * 32 + lc],
               &As[cur ^ 1][r0 * 32]);
        GLDS16(&W[(size_t)(colBase + r0 + lr) * 1024 + (kt + 1) * 32 + lc],
               &Bs[cur ^ 1][r0 * 32]);
      }
    }
    bf16x8 af[4], bfr[4];
#pragma unroll
    for (int i = 0; i < 4; i++)
      af[i] = *(const bf16x8*)&As[cur][(wr * 64 + i * 16 + m) * 32 + quad * 8];
#pragma unroll
    for (int j2 = 0; j2 < 4; j2++)
      bfr[j2] = *(const bf16x8*)&Bs[cur][(wc * 64 + j2 * 16 + m) * 32 + quad * 8];
#pragma unroll
    for (int i = 0; i < 4; i++)
#pragma unroll
      for (int j2 = 0; j2 < 4; j2++) acc[i][j2] = MFMA16(af[i], bfr[j2], acc[i][j2]);
    __syncthreads();
  }

#pragma unroll
  for (int j2 = 0; j2 < 4; j2++) {
    const int col = colBase + wc * 64 + j2 * 16 + m;
    const float bv_ = bias[col];
#pragma unroll
    for (int i = 0; i < 4; i++) {
#pragma unroll
      for (int r = 0; r < 4; r++) {
        const int row = rowBase + wr * 64 + i * 16 + quad * 4 + r;
        Out[(size_t)row * 1024 + col] = acc[i][j2][r] + bv_;
      }
    }
  }
}

// ---------------------------------------------------------------------------
// Flash attention v9 (unchanged -- passed rounds 9/10):
// block-cooperative LDS staging of K/V^T (8 waves share), double-buffered
// with prefetch-before-compute; swapped QK^T -> per-lane scalar online
// softmax; defer-max THR=8; cvt_pk P-pack; XOR-granule swizzled staging.
// ---------------------------------------------------------------------------
__global__ __launch_bounds__(512) void attn(
    const u16t* __restrict__ Q, const u16t* __restrict__ K,
    const u16t* __restrict__ VT, const int* __restrict__ ids,
    u16t* __restrict__ Oo) {
  constexpr int PSTR = 72;
  __shared__ __align__(16) u16t Kb[2][64 * 64];
  __shared__ __align__(16) u16t Vb[2][64 * 64];
  __shared__ __align__(16) u16t Ps[8][16 * PSTR];
  __shared__ unsigned long long maskL[16];

  const int t = threadIdx.x, lane = t & 63, wl = t >> 6;  // wl: 0..7
  const int m = lane & 15, quad = lane >> 4;
  const int id = blockIdx.x;
  const int g = id & 7, k_ = id >> 3;
  const int bh = g + 8 * (k_ & 15);
  const int p4 = k_ >> 4;                // 0..3
  const int b = bh >> 4, h = bh & 15;
  const size_t hoff = (size_t)bh * 65536;   // 1024 * 64

  const int srow = lane >> 3;
  const int sg = (lane & 7) ^ (srow & 7);

#pragma unroll
  for (int c = 0; c < 2; ++c) {
    const int chunk = wl * 2 + c;
    const int idv = ids[b * 1024 + chunk * 64 + lane];
    const unsigned long long mk = __ballot(idv != 1);
    if (lane == 0) maskL[chunk] = mk;
  }
  __syncthreads();

  u16t* const Pw = &Ps[wl][0];

  for (int pass = 0; pass < 2; ++pass) {
    const int qt8 = pass ? (7 - p4) : p4;
    const int qbase = qt8 * 128 + wl * 16;
    const int qrow = qbase + m;          // this lane's softmax row
    const int ktmax = 2 * qt8 + 1;

    GLDS16(&K[hoff + (size_t)(wl * 8 + srow) * 64 + sg * 8], &Kb[0][wl * 512]);
    GLDS16(&VT[hoff + (size_t)(wl * 8 + srow) * 1024 + sg * 8], &Vb[0][wl * 512]);

    const bf16x8 qf0 =
        *(const bf16x8*)&Q[hoff + (size_t)(qbase + m) * 64 + quad * 8];
    const bf16x8 qf1 =
        *(const bf16x8*)&Q[hoff + (size_t)(qbase + m) * 64 + 32 + quad * 8];

    float mi = MASKV, li = 0.f;
    f32x4 o[4];
#pragma unroll
    for (int ot = 0; ot < 4; ot++) o[ot] = (f32x4){0.f, 0.f, 0.f, 0.f};

    __syncthreads();   // buf0 staged (drains vmcnt)

    for (int kt = 0; kt <= ktmax; ++kt) {
      if (kt < ktmax) {
        u16t* const kb = &Kb[(kt + 1) & 1][wl * 512];
        u16t* const vb = &Vb[(kt + 1) & 1][wl * 512];
        GLDS16(&K[hoff + (size_t)((kt + 1) * 64 + wl * 8 + srow) * 64 + sg * 8], kb);
        GLDS16(&VT[hoff + (size_t)(wl * 8 + srow) * 1024 + (kt + 1) * 64 + sg * 8], vb);
      }

      if (kt * 64 <= qbase + 15) {       // wave-uniform: any causal work?
        const u16t* const Kc = Kb[kt & 1];
        const u16t* const Vc = Vb[kt & 1];

        const int dq0 = qrow - kt * 64;            // >= 0 inside guard
        const int dqc = dq0 > 63 ? 63 : dq0;
        const unsigned long long causal =
            (dqc == 63) ? ~0ull : ((1ull << (dqc + 1)) - 1ull);
        const unsigned long long km2 = maskL[kt] & causal;
        const unsigned kqlo = (unsigned)(km2 >> (quad * 4));
        const unsigned kqhi = (unsigned)(km2 >> (quad * 4 + 32));

        f32x4 sc[4];
        float pm = MASKV;
#pragma unroll
        for (int nt = 0; nt < 4; nt++) {
          if ((kt * 64 + nt * 16) <= (qbase + 15)) { // wave-uniform skip
            const int krow = (nt * 16 + m) * 64;
            const bf16x8 k0 =
                *(const bf16x8*)&Kc[krow + ((quad ^ (m & 7)) & 7) * 8];
            const bf16x8 k1 =
                *(const bf16x8*)&Kc[krow + (((quad + 4) ^ (m & 7)) & 7) * 8];
            f32x4 c = (f32x4){0.f, 0.f, 0.f, 0.f};
            c = MFMA16(k0, qf0, c);     // SWAPPED: A=K (row=key), B=Q (col=q)
            c = MFMA16(k1, qf1, c);
            const unsigned w32 = (nt < 2) ? kqlo : kqhi;
#pragma unroll
            for (int r = 0; r < 4; r++) {
              const int sh = (nt & 1) * 16 + r;      // compile-time
              const float s = ((w32 >> sh) & 1u) ? c[r] * 0.125f : MASKV;
              sc[nt][r] = s;
              pm = fmaxf(pm, s);
            }
          } else {
#pragma unroll
            for (int r = 0; r < 4; r++) sc[nt][r] = MASKV;
          }
        }
        pm = fmaxf(pm, __shfl_xor(pm, 16));
        pm = fmaxf(pm, __shfl_xor(pm, 32));

        if (__any(pm > mi + 8.0f)) {
          const float mn = (pm > mi + 8.0f) ? pm : mi;
          const float alpha = exp2f((mi - mn) * L2E);
          mi = mn;
          li *= alpha;
#pragma unroll
          for (int r = 0; r < 4; r++) {
            const float ar = __shfl(alpha, quad * 4 + r);
#pragma unroll
            for (int ot = 0; ot < 4; ot++) o[ot][r] *= ar;
          }
        }

        float rsum = 0.f;
#pragma unroll
        for (int nt = 0; nt < 4; nt++) {
          float pf[4];
#pragma unroll
          for (int r = 0; r < 4; r++) {
            pf[r] = exp2f((sc[nt][r] - mi) * L2E);  // masked -> 0
            rsum += pf[r];
          }
          unsigned w0, w1;
          asm("v_cvt_pk_bf16_f32 %0, %1, %2" : "=v"(w0) : "v"(pf[0]), "v"(pf[1]));
          asm("v_cvt_pk_bf16_f32 %0, %1, %2" : "=v"(w1) : "v"(pf[2]), "v"(pf[3]));
          uint2 wv; wv.x = w0; wv.y = w1;
          *(uint2*)&Pw[m * PSTR + nt * 16 + quad * 4] = wv;
        }
        rsum += __shfl_xor(rsum, 16);
        rsum += __shfl_xor(rsum, 32);
        li += rsum;

        const bf16x8 p0 = *(const bf16x8*)&Pw[m * PSTR + quad * 8];
        const bf16x8 p1 = *(const bf16x8*)&Pw[m * PSTR + 32 + quad * 8];
#pragma unroll
        for (int ot = 0; ot < 4; ot++) {
          const int vrow = (ot * 16 + m) * 64;
          const bf16x8 v0 =
              *(const bf16x8*)&Vc[vrow + ((quad ^ (m & 7)) & 7) * 8];
          const bf16x8 v1 =
              *(const bf16x8*)&Vc[vrow + (((quad + 4) ^ (m & 7)) & 7) * 8];
          o[ot] = MFMA16(p0, v0, o[ot]);
          o[ot] = MFMA16(p1, v1, o[ot]);
        }
      }

      __syncthreads();  // next tile staged + all reads of cur tile complete
    }

    const float linv = (li > 1e-30f) ? 1.f / li : 0.f;
#pragma unroll
    for (int r = 0; r < 4; r++) {
      const float inv = __shfl(linv, quad * 4 + r);
      const int qo = qbase + quad * 4 + r;
#pragma unroll
      for (int ot = 0; ot < 4; ot++) {
        const int col = h * 64 + ot * 16 + m;
        Oo[((size_t)(b * 1024 + qo)) * 1024 + col] = f2b(o[ot][r] * inv);
      }
    }
  }
}

// ---------------------------------------------------------------------------
extern "C" void kernel_launch(void* const* d_in, const int* in_sizes, int n_in,
                              void* d_out, int out_size, void* d_ws, size_t ws_size,
                              hipStream_t stream) {
  const float* x  = (const float*)d_in[0];
  const int*   ids = (const int*)d_in[1];
  const float* Wq = (const float*)d_in[2];
  const float* bq = (const float*)d_in[3];
  const float* Wk = (const float*)d_in[4];
  const float* bk = (const float*)d_in[5];
  const float* Wv = (const float*)d_in[6];
  const float* bv = (const float*)d_in[7];
  const float* Wo = (const float*)d_in[8];
  const float* bo = (const float*)d_in[9];
  float* out = (float*)d_out;

  // ws layout (bf16 elems): XB 8.4M | WqB,WkB,WvB,WoB 1M each | Q,K,V 8.4M each
  u16t* XB  = (u16t*)d_ws;
  u16t* WqB = XB  + 8388608;
  u16t* WkB = WqB + 1048576;
  u16t* WvB = WkB + 1048576;
  u16t* WoB = WvB + 1048576;
  u16t* Qw  = WoB + 1048576;
  u16t* Kw  = Qw  + 8388608;
  u16t* Vw  = Kw  + 8388608;   // holds V^T[b][h][hd][s]
  u16t* AO  = XB; // reuse after gemm_qkv consumed XB

  cvt5<<<6144, 256, 0, stream>>>(x, Wq, Wk, Wv, Wo, XB, WqB, WkB, WvB, WoB);
  gemm_qkv<<<1536, 256, 0, stream>>>(XB, WqB, WkB, WvB, bq, bk, bv, Qw, Kw, Vw);
  attn<<<512, 512, 0, stream>>>(Qw, Kw, Vw, ids, AO);
  gemm_o<<<512, 256, 0, stream>>>(AO, WoB, bo, out);
}